// Round 1
// baseline (224.666 us; speedup 1.0000x reference)
//
#include <hip/hip_runtime.h>

#define HW 4096
#define CDIM 256
#define BK 32

typedef _Float16 half8 __attribute__((ext_vector_type(8)));
typedef float f32x4 __attribute__((ext_vector_type(4)));

__device__ __forceinline__ void top3_ins(float v, float& a0, float& a1, float& a2) {
  float m01 = fminf(a0, v);
  a0 = fmaxf(a0, v);
  float m12 = fminf(a1, m01);
  a1 = fmaxf(a1, m01);
  a2 = fmaxf(a2, m12);
}

__device__ __forceinline__ float mask_val(const float* gtab, int s, int t) {
  int dr = (s >> 6) - (t >> 6); dr = dr < 0 ? -dr : dr;
  int dc = (s & 63) - (t & 63); dc = dc < 0 ? -dc : dc;
  return 1.0f - gtab[dr] * gtab[dc];
}

__device__ __forceinline__ void async_copy16(const void* g, void* l) {
  __builtin_amdgcn_global_load_lds((const __attribute__((address_space(1))) void*)g,
                                   (__attribute__((address_space(3))) void*)l, 16, 0, 0);
}

// Swizzled LDS staging (unchanged from proven kernel): slot(lane) = (row=lane>>2,
// chunk'=lane&3); receives GLOBAL chunk c = (chunk' - (row>>1)) & 3 so readers at
// chunk' = (q + (row>>1)) & 3 see global chunk q. 2-way LDS aliasing (free).
__device__ __forceinline__ void stage_slice(const _Float16* __restrict__ X,
                                            int rowBase, int k0,
                                            _Float16* sdst, int w, int lane) {
  const int csrc = ((lane & 3) - ((lane >> 3) & 3)) & 3;
#pragma unroll
  for (int i = 0; i < 2; ++i) {
    const int rchunk = w * 32 + i * 16;
    const _Float16* g =
        X + (size_t)(rowBase + rchunk + (lane >> 2)) * CDIM + k0 + csrc * 8;
    async_copy16(g, sdst + rchunk * BK);  // HW appends lane*16B
  }
}

// ---------------- kernel 1: channel-L2 normalize + fp16 transpose ----------------
__global__ void __launch_bounds__(256) normalize_k(const float* __restrict__ x,
                                                   _Float16* __restrict__ Xf) {
  const int p = threadIdx.x & 31;
  const int g = threadIdx.x >> 5;
  const int P0 = blockIdx.x * 32;
  const int b = P0 >> 12;
  const int ph = (P0 & (HW - 1)) + p;
  const float* xb = x + (size_t)b * CDIM * HW + ph;
  float vals[32];
  float ss = 0.f;
#pragma unroll
  for (int k = 0; k < 32; ++k) {
    float v = xb[(size_t)(g * 32 + k) * HW];
    vals[k] = v;
    ss += v * v;
  }
  __shared__ float ssqp[8][33];
  __shared__ float scl[32];
  ssqp[g][p] = ss;
  __syncthreads();
  if (threadIdx.x < 32) {
    float s2 = 0.f;
#pragma unroll
    for (int gg = 0; gg < 8; ++gg) s2 += ssqp[gg][threadIdx.x];
    scl[threadIdx.x] = 1.0f / fmaxf(sqrtf(s2), 1e-12f);
  }
  __syncthreads();
  const float sc = scl[p];
  _Float16* o = Xf + (size_t)(P0 + p) * CDIM + g * 32;
#pragma unroll
  for (int c8 = 0; c8 < 4; ++c8) {
    half8 h;
#pragma unroll
    for (int j = 0; j < 8; ++j) h[j] = (_Float16)(vals[c8 * 8 + j] * sc);
    *(half8*)(o + c8 * 8) = h;
  }
}

// ---------------- shared GEMM mainloop: 128x128 tile, 4 waves of 64x64 ----------------
__device__ __forceinline__ void gemm_mainloop(const _Float16* __restrict__ X,
                                              int mBase, int nBase, int lane, int w,
                                              _Float16 (*sA)[128 * BK],
                                              _Float16 (*sB)[128 * BK],
                                              f32x4 (&acc)[4][4]) {
  const int wr = w >> 1, wc = w & 1;
#pragma unroll
  for (int mi = 0; mi < 4; ++mi)
#pragma unroll
    for (int ni = 0; ni < 4; ++ni) acc[mi][ni] = (f32x4){0.f, 0.f, 0.f, 0.f};

  const int aRow0 = wr * 64 + (lane & 15);
  const int bRow0 = wc * 64 + (lane & 15);
  const int cswz = (((lane >> 4) + ((lane >> 1) & 3)) & 3) * 8;

  stage_slice(X, mBase, 0, sA[0], w, lane);
  stage_slice(X, nBase, 0, sB[0], w, lane);

  int cur = 0;
#pragma unroll
  for (int k0 = 0; k0 < CDIM; k0 += BK) {
    __syncthreads();
    if (k0 + BK < CDIM) {
      stage_slice(X, mBase, k0 + BK, sA[cur ^ 1], w, lane);
      stage_slice(X, nBase, k0 + BK, sB[cur ^ 1], w, lane);
    }
    half8 a[4], bfr[4];
#pragma unroll
    for (int i = 0; i < 4; ++i)
      a[i] = *(const half8*)(sA[cur] + (aRow0 + 16 * i) * BK + cswz);
#pragma unroll
    for (int i = 0; i < 4; ++i)
      bfr[i] = *(const half8*)(sB[cur] + (bRow0 + 16 * i) * BK + cswz);
#pragma unroll
    for (int mi = 0; mi < 4; ++mi)
#pragma unroll
      for (int ni = 0; ni < 4; ++ni)
        acc[mi][ni] = __builtin_amdgcn_mfma_f32_16x16x32_f16(a[mi], bfr[ni], acc[mi][ni], 0, 0, 0);
    cur ^= 1;
  }
}

// ---------------- kernel 2: GEMM pass 1 -> R[t] = col sums of E (== row sums) ----------------
__global__ void __launch_bounds__(256, 3) gemmR_k(const _Float16* __restrict__ Xf,
                                                  const float* __restrict__ alphap,
                                                  float* __restrict__ R) {
  __shared__ _Float16 sA[2][128 * BK];
  __shared__ _Float16 sB[2][128 * BK];
  __shared__ float gtab[64];
  if (threadIdx.x < 64) {
    float d = (float)threadIdx.x;
    gtab[threadIdx.x] = __expf(-d * d * 0.048828125f);
  }
  const float alpha = alphap[0];
  const int b = blockIdx.z;
  const _Float16* X = Xf + (size_t)b * HW * CDIM;
  const int lane = threadIdx.x & 63;
  const int w = threadIdx.x >> 6;
  const int wr = w >> 1, wc = w & 1;
  const int mBase = blockIdx.y * 128;
  const int nBase = blockIdx.x * 128;

  f32x4 acc[4][4];
  gemm_mainloop(X, mBase, nBase, lane, w, sA, sB, acc);

  const int quad = lane >> 4;
  float csum[4] = {0.f, 0.f, 0.f, 0.f};
#pragma unroll
  for (int mi = 0; mi < 4; ++mi) {
#pragma unroll
    for (int r = 0; r < 4; ++r) {
      const int s = mBase + wr * 64 + mi * 16 + quad * 4 + r;
#pragma unroll
      for (int ni = 0; ni < 4; ++ni) {
        const int t = nBase + wc * 64 + ni * 16 + (lane & 15);
        csum[ni] += __expf(alpha * mask_val(gtab, s, t) * acc[mi][ni][r]);
      }
    }
  }
#pragma unroll
  for (int off = 16; off < 64; off <<= 1)
#pragma unroll
    for (int ni = 0; ni < 4; ++ni) csum[ni] += __shfl_xor(csum[ni], off);
  if (quad == 0) {
#pragma unroll
    for (int ni = 0; ni < 4; ++ni)
      atomicAdd(&R[b * HW + nBase + wc * 64 + ni * 16 + (lane & 15)], csum[ni]);
  }
}

// ---- kernel 3: GEMM pass 2 -> per (s-block, t) partials {sum(g), top3(g)}, g = E^2/R[s] ----
__global__ void __launch_bounds__(256, 3) gemmT_k(const _Float16* __restrict__ Xf,
                                                  const float* __restrict__ alphap,
                                                  const float* __restrict__ R,
                                                  float* __restrict__ part) {
  __shared__ _Float16 sA[2][128 * BK];
  __shared__ _Float16 sB[2][128 * BK];
  __shared__ float gtab[64];
  __shared__ float sRinv[128];
  __shared__ float sStats[2][128][4];
  const int b = blockIdx.z;
  const int mBase = blockIdx.y * 128;
  const int nBase = blockIdx.x * 128;
  if (threadIdx.x < 64) {
    float d = (float)threadIdx.x;
    gtab[threadIdx.x] = __expf(-d * d * 0.048828125f);
  }
  if (threadIdx.x < 128)
    sRinv[threadIdx.x] = 1.0f / R[b * HW + mBase + threadIdx.x];
  const float alpha = alphap[0];
  const _Float16* X = Xf + (size_t)b * HW * CDIM;
  const int lane = threadIdx.x & 63;
  const int w = threadIdx.x >> 6;
  const int wr = w >> 1, wc = w & 1;

  f32x4 acc[4][4];
  gemm_mainloop(X, mBase, nBase, lane, w, sA, sB, acc);

  const int quad = lane >> 4;
  float tsum[4] = {0.f, 0.f, 0.f, 0.f};
  float q0[4] = {0.f, 0.f, 0.f, 0.f}, q1[4] = {0.f, 0.f, 0.f, 0.f}, q2[4] = {0.f, 0.f, 0.f, 0.f};
#pragma unroll
  for (int mi = 0; mi < 4; ++mi) {
#pragma unroll
    for (int r = 0; r < 4; ++r) {
      const int lrow = wr * 64 + mi * 16 + quad * 4 + r;
      const int s = mBase + lrow;
      const float inv = sRinv[lrow];
#pragma unroll
      for (int ni = 0; ni < 4; ++ni) {
        const int t = nBase + wc * 64 + ni * 16 + (lane & 15);
        float e = __expf(alpha * mask_val(gtab, s, t) * acc[mi][ni][r]);
        float g = e * e * inv;
        tsum[ni] += g;
        top3_ins(g, q0[ni], q1[ni], q2[ni]);
      }
    }
  }
  // combine across the 4 quads (rows quad*4+r of each 16-row fragment)
#pragma unroll
  for (int off = 16; off < 64; off <<= 1) {
#pragma unroll
    for (int ni = 0; ni < 4; ++ni) {
      tsum[ni] += __shfl_xor(tsum[ni], off);
      float b0 = __shfl_xor(q0[ni], off);
      float b1 = __shfl_xor(q1[ni], off);
      float b2 = __shfl_xor(q2[ni], off);
      top3_ins(b0, q0[ni], q1[ni], q2[ni]);
      top3_ins(b1, q0[ni], q1[ni], q2[ni]);
      top3_ins(b2, q0[ni], q1[ni], q2[ni]);
    }
  }
  if (quad == 0) {
#pragma unroll
    for (int ni = 0; ni < 4; ++ni) {
      const int col = wc * 64 + ni * 16 + (lane & 15);
      sStats[wr][col][0] = tsum[ni];
      sStats[wr][col][1] = q0[ni];
      sStats[wr][col][2] = q1[ni];
      sStats[wr][col][3] = q2[ni];
    }
  }
  __syncthreads();
  if (threadIdx.x < 128) {
    float su = sStats[0][threadIdx.x][0] + sStats[1][threadIdx.x][0];
    float a0 = sStats[0][threadIdx.x][1];
    float a1 = sStats[0][threadIdx.x][2];
    float a2 = sStats[0][threadIdx.x][3];
    top3_ins(sStats[1][threadIdx.x][1], a0, a1, a2);
    top3_ins(sStats[1][threadIdx.x][2], a0, a1, a2);
    top3_ins(sStats[1][threadIdx.x][3], a0, a1, a2);
    f32x4 o = {su, a0, a1, a2};
    *(f32x4*)(part + ((size_t)(b * 32 + blockIdx.y) * HW + nBase + threadIdx.x) * 4) = o;
  }
}

// -------- kernel 4: fold 32 s-block partials -> val, W[t] = 1/(T + 1e-8*R[t]) --------
__global__ void __launch_bounds__(256) merge_k(const float* __restrict__ R,
                                               const float* __restrict__ part,
                                               float* __restrict__ W,
                                               float* __restrict__ val_out) {
  const int idx = blockIdx.x * 256 + threadIdx.x;
  const int b = idx >> 12;
  const int t = idx & (HW - 1);
  float T = 0.f, a0 = 0.f, a1 = 0.f, a2 = 0.f;
#pragma unroll 8
  for (int sblk = 0; sblk < 32; ++sblk) {
    f32x4 p = *(const f32x4*)(part + ((size_t)(b * 32 + sblk) * HW + t) * 4);
    T += p[0];
    top3_ins(p[1], a0, a1, a2);
    top3_ins(p[2], a0, a1, a2);
    top3_ins(p[3], a0, a1, a2);
  }
  const float r = R[idx];
  const float invr = 1.0f / r;
  val_out[(b * 3 + 0) * HW + t] = a0 * invr;  // col-sum C_t == R_t by symmetry
  val_out[(b * 3 + 1) * HW + t] = a1 * invr;
  val_out[(b * 3 + 2) * HW + t] = a2 * invr;
  W[idx] = 1.0f / (T + 1e-8f * r);
}

// ---- kernel 5: GEMM pass 3 -> x_soft = E^2 * invR[s] * W[t], written directly ----
__global__ void __launch_bounds__(256, 3) gemmW_k(const _Float16* __restrict__ Xf,
                                                  const float* __restrict__ alphap,
                                                  const float* __restrict__ R,
                                                  const float* __restrict__ W,
                                                  float* __restrict__ outX) {
  __shared__ _Float16 sA[2][128 * BK];
  __shared__ _Float16 sB[2][128 * BK];
  __shared__ float gtab[64];
  __shared__ float sRinv[128];
  __shared__ float sWc[128];
  const int b = blockIdx.z;
  const int mBase = blockIdx.y * 128;
  const int nBase = blockIdx.x * 128;
  if (threadIdx.x < 64) {
    float d = (float)threadIdx.x;
    gtab[threadIdx.x] = __expf(-d * d * 0.048828125f);
  }
  if (threadIdx.x < 128) {
    sRinv[threadIdx.x] = 1.0f / R[b * HW + mBase + threadIdx.x];
    sWc[threadIdx.x] = W[b * HW + nBase + threadIdx.x];
  }
  const float alpha = alphap[0];
  const _Float16* X = Xf + (size_t)b * HW * CDIM;
  const int lane = threadIdx.x & 63;
  const int w = threadIdx.x >> 6;
  const int wr = w >> 1, wc = w & 1;

  f32x4 acc[4][4];
  gemm_mainloop(X, mBase, nBase, lane, w, sA, sB, acc);

  const int quad = lane >> 4;
  float* Xb = outX + (size_t)b * HW * HW;
#pragma unroll
  for (int mi = 0; mi < 4; ++mi) {
#pragma unroll
    for (int r = 0; r < 4; ++r) {
      const int lrow = wr * 64 + mi * 16 + quad * 4 + r;
      const int s = mBase + lrow;
      const float inv = sRinv[lrow];
      float* orow = Xb + (size_t)s * HW;
#pragma unroll
      for (int ni = 0; ni < 4; ++ni) {
        const int col = wc * 64 + ni * 16 + (lane & 15);
        const int t = nBase + col;
        float e = __expf(alpha * mask_val(gtab, s, t) * acc[mi][ni][r]);
        orow[t] = e * e * inv * sWc[col];
      }
    }
  }
}

extern "C" void kernel_launch(void* const* d_in, const int* in_sizes, int n_in,
                              void* d_out, int out_size, void* d_ws, size_t ws_size,
                              hipStream_t stream) {
  const float* x = (const float*)d_in[0];
  const float* alphap = (const float*)d_in[1];
  float* out = (float*)d_out;
  float* out_val = out;                 // (b,3,h,w) = 24576 floats
  float* out_x = out + 2 * 3 * HW;      // (b,hw,h,w) final x_soft; used as scratch first
  char* ws = (char*)d_ws;

  _Float16* Xf = (_Float16*)ws;                      // 4 MB
  float* R = (float*)(ws + (size_t)4194304);         // 32 KB
  float* W = R + 2 * HW;                             // 32 KB
  float* part = out_x;                               // 4 MB partials in out_x scratch,
                                                     // fully overwritten by gemmW_k

  hipMemsetAsync(R, 0, (size_t)2 * HW * sizeof(float), stream);

  normalize_k<<<dim3(256), dim3(256), 0, stream>>>(x, Xf);
  gemmR_k<<<dim3(32, 32, 2), dim3(256), 0, stream>>>(Xf, alphap, R);
  gemmT_k<<<dim3(32, 32, 2), dim3(256), 0, stream>>>(Xf, alphap, R, part);
  merge_k<<<dim3(32), dim3(256), 0, stream>>>(R, part, W, out_val);
  gemmW_k<<<dim3(32, 32, 2), dim3(256), 0, stream>>>(Xf, alphap, R, W, out_x);
}